// Round 9
// baseline (420.432 us; speedup 1.0000x reference)
//
#include <hip/hip_runtime.h>
#include <hip/hip_bf16.h>
#include <hip/hip_fp16.h>

// SwinV2 window attention, MI355X/gfx950.
// Pipeline: cvt_w, cpb, rpb (1MB natural-layout bias, log2e-folded),
//           2x [cvt_x(half) -> attn(half)], proj.
// attn: 1024 thr / 16 waves, 2 blocks/CU (LDS 77824, VGPR<=64).
// R9: k-slot-PERMUTED operand layouts (slot lg, j<4 <-> elem lg*4+j, j>=4
// <-> 16+lg*4+(j-4)) so aq and pa are packed from the lane's OWN registers
// (zero cross-lane exchange), PV is swapped (mfma(V-frag, P)) so o lands at
// [d][q=l16] and rescale/normalize are lane-local, lk store is one b128,
// lv stored token-permuted to match. DS-pipe ops per chunk drop ~3x.

#define LOG100F 4.605170185988091f
#define LOG2EF 1.4426950408889634f

typedef __attribute__((ext_vector_type(8))) __bf16 bf16x8;
typedef __attribute__((ext_vector_type(4))) float f32x4;
typedef __attribute__((ext_vector_type(8))) unsigned short u16x8;
typedef __attribute__((ext_vector_type(4))) unsigned short u16x4;
typedef __attribute__((ext_vector_type(4))) unsigned int u32x4;

__device__ __forceinline__ unsigned short f2bfu(float f) {
  __hip_bfloat16 b = __float2bfloat16(f);
  return __builtin_bit_cast(unsigned short, b);
}
__device__ __forceinline__ unsigned short f2h(float f) {
  __half hv = __float2half(f);
  return __builtin_bit_cast(unsigned short, hv);
}
__device__ __forceinline__ float h2f(unsigned short b) {
  return __half2float(__builtin_bit_cast(__half, b));
}
__device__ __forceinline__ bf16x8 lds8(const unsigned short* p) {
  u16x8 v = *(const u16x8*)p;
  return __builtin_bit_cast(bf16x8, v);
}
__device__ __forceinline__ f32x4 mfma16(bf16x8 a, bf16x8 b, f32x4 c) {
  return __builtin_amdgcn_mfma_f32_16x16x32_bf16(a, b, c, 0, 0, 0);
}
__device__ __forceinline__ float fexp2(float x) {
#if __has_builtin(__builtin_amdgcn_exp2f)
  return __builtin_amdgcn_exp2f(x);
#else
  return exp2f(x);
#endif
}
// pack two f32 -> one u32 of 2 bf16 (lo = a, hi = b), RNE
__device__ __forceinline__ unsigned int cvtpk(float a, float b) {
  unsigned int r;
  asm("v_cvt_pk_bf16_f32 %0, %1, %2" : "=v"(r) : "v"(a), "v"(b));
  return r;
}
// 16B-chunk XOR swizzle for [R][32]-u16 tiles: <=2-way on ds_read_b128
__device__ __forceinline__ int swc(int row, int kchunk) {
  return (kchunk ^ (row & 3) ^ ((row >> 2) & 3)) & 3;
}
__device__ __forceinline__ void gload_lds16(const void* g, void* l) {
  __builtin_amdgcn_global_load_lds(
      (const __attribute__((address_space(1))) void*)g,
      (__attribute__((address_space(3))) void*)l, 16, 0, 0);
}

// ---------------- weights -> bf16 ----------------
__global__ void k_cvt_w(const float* __restrict__ qkv_w, const float* __restrict__ proj_w,
                        unsigned short* __restrict__ wqkv, unsigned short* __restrict__ wproj) {
  const int t = blockIdx.x * 256 + threadIdx.x;
  if (t < 768 * 256) {
    wqkv[t] = f2bfu(qkv_w[t]);
  } else {
    const int t2 = t - 768 * 256;
    wproj[t2] = f2bfu(proj_w[t2]);
  }
}

// ---------------- x -> bf16 (half batch per call) ----------------
__global__ void k_cvt_x(const float* __restrict__ x, unsigned short* __restrict__ xb) {
  const int t = blockIdx.x * 256 + threadIdx.x;
  const float4 a = *(const float4*)(x + (size_t)t * 8);
  const float4 c = *(const float4*)(x + (size_t)t * 8 + 4);
  u16x8 ov;
  ov[0] = f2bfu(a.x); ov[1] = f2bfu(a.y); ov[2] = f2bfu(a.z); ov[3] = f2bfu(a.w);
  ov[4] = f2bfu(c.x); ov[5] = f2bfu(c.y); ov[6] = f2bfu(c.z); ov[7] = f2bfu(c.w);
  *(u16x8*)(xb + (size_t)t * 8) = ov;
}

// ---------------- CPB MLP -> bias_table[961][8] ----------------
__global__ void k_cpb(const float* __restrict__ w1, const float* __restrict__ b1,
                      const float* __restrict__ w2, float* __restrict__ bt) {
  const int row = blockIdx.x;
  const int lane = threadIdx.x;
  const int i = row / 31, j = row % 31;
  float x0 = (i - 15) * (1.0f / 15.0f);
  float x1 = (j - 15) * (1.0f / 15.0f);
  float v0 = log2f(fmaf(8.0f, fabsf(x0), 1.0f)) * (1.0f / 3.0f); v0 = x0 < 0.0f ? -v0 : v0;
  float v1 = log2f(fmaf(8.0f, fabsf(x1), 1.0f)) * (1.0f / 3.0f); v1 = x1 < 0.0f ? -v1 : v1;
  float a[8] = {0.f, 0.f, 0.f, 0.f, 0.f, 0.f, 0.f, 0.f};
  for (int jj = lane; jj < 512; jj += 64) {
    float hv = fmaf(w1[2 * jj], v0, fmaf(w1[2 * jj + 1], v1, b1[jj]));
    hv = fmaxf(hv, 0.0f);
#pragma unroll
    for (int hh = 0; hh < 8; ++hh) a[hh] = fmaf(hv, w2[hh * 512 + jj], a[hh]);
  }
#pragma unroll
  for (int hh = 0; hh < 8; ++hh) {
#pragma unroll
    for (int mm = 1; mm < 64; mm <<= 1) a[hh] += __shfl_xor(a[hh], mm);
  }
  float outv = a[0];
#pragma unroll
  for (int hh = 1; hh < 8; ++hh)
    if (lane == hh) outv = a[hh];
  if (lane < 8) bt[row * 8 + lane] = outv;
}

// ------- rpbn[h][n][m] = fp16(log2e * 16*sigmoid(bt[idx(n,m)][h])) -------
__global__ void k_rpb(const float* __restrict__ bt, unsigned short* __restrict__ rpbn) {
  const int t = blockIdx.x * 256 + threadIdx.x;  // 2048 blocks -> 524288
  const int m = t & 255, n = (t >> 8) & 255, h = t >> 16;
  const int ih = n >> 4, iw = n & 15, jh = m >> 4, jw = m & 15;
  const int idx = (ih - jh + 15) * 31 + (iw - jw + 15);
  const float bv = bt[idx * 8 + h];
  rpbn[t] = f2h(LOG2EF * 16.0f / (1.0f + __expf(-bv)));
}

// ---------------- fused qkv + cosine attention, per (b,h) ----------------
__global__ __launch_bounds__(1024, 8) void k_attn(
    const unsigned short* __restrict__ xb, const float* __restrict__ q_bias,
    const float* __restrict__ v_bias, const float* __restrict__ logit_scale,
    const unsigned short* __restrict__ wqkv, const unsigned short* __restrict__ rpbn,
    const float* __restrict__ mask, unsigned short* __restrict__ Obuf, int b0) {
  // 77,824 B total -> 2 blocks/CU.
  __shared__ unsigned short lx[2][8192];  // x slice [256 tok][32 k], dbuf (phase A only)
  __shared__ unsigned short lw[2][3072];  // W_h slice [96][32], dbuf
  __shared__ unsigned short lk[8192];     // k-hat [256 tok][32 d], d-permuted chunks
  __shared__ unsigned short lv[8192];     // v^T  [32 d][256 tok], token-permuted chunks

  // XCD-aware map: bid = g*64 + h*8 + x (x = XCD = bid%8); bl = g*8 + x.
  const int bid = blockIdx.x;
  const int xcd = bid & 7, h = (bid >> 3) & 7, g = bid >> 6;
  const int bl = g * 8 + xcd;
  const int b = b0 + bl;
  const int w = b & 63;
  const int tid = threadIdx.x;
  const int lane = tid & 63, wid = tid >> 6;
  const int l16 = lane & 15, lg = lane >> 4;

  // ---- phase A: [96 wcols x 256 tok] = W_h . x^T, K=256 in 8 slices ----
  const int srow = wid * 16 + (lane >> 2);
  const int pc = lane & 3;
  const int xlc = (pc ^ (srow & 3) ^ ((srow >> 2) & 3)) & 3;
  const unsigned short* xsrc0 = xb + (((bl << 8) + srow) << 8) + (xlc << 3);
  const unsigned short* wsrc0 =
      wqkv + ((((srow >> 5) << 8) + h * 32 + (srow & 31)) << 8) + (xlc << 3);

  f32x4 acc[6];
#pragma unroll
  for (int i = 0; i < 6; ++i) acc[i] = (f32x4){0.f, 0.f, 0.f, 0.f};

  gload_lds16(xsrc0, &lx[0][wid * 512]);
  if (wid < 6) gload_lds16(wsrc0, &lw[0][wid * 512]);
  __syncthreads();

  for (int kt = 0; kt < 8; ++kt) {
    const int cur = kt & 1;
    if (kt < 7) {
      const int k0 = (kt + 1) << 5;
      gload_lds16(xsrc0 + k0, &lx[cur ^ 1][wid * 512]);
      if (wid < 6) gload_lds16(wsrc0 + k0, &lw[cur ^ 1][wid * 512]);
    }
    const unsigned short* lxb = lx[cur];
    const unsigned short* lwb = lw[cur];
    const int n = wid * 16 + l16;
    const bf16x8 ax = lds8(lxb + n * 32 + (swc(n, lg) << 3));
#pragma unroll
    for (int mf = 0; mf < 6; ++mf) {
      const int m = mf * 16 + l16;
      const bf16x8 aw = lds8(lwb + m * 32 + (swc(m, lg) << 3));
      acc[mf] = mfma16(aw, ax, acc[mf]);
    }
    __syncthreads();
  }

  // ---- epilogue: lane owns token tok = wid*16+l16; d = mf*16+lg*4+r ----
  // k-slot mapping (QK): slot lg, j<4 <-> d = lg*4+j ; j>=4 <-> d = 16+lg*4+(j-4).
  const float sl = __expf(fminf(logit_scale[h], LOG100F)) * LOG2EF;
  const int tok = wid * 16 + l16;
  const float4 qb0 = *(const float4*)(q_bias + h * 32 + lg * 4);
  const float4 qb1 = *(const float4*)(q_bias + h * 32 + 16 + lg * 4);

  bf16x8 aq;  // B-frag for QK, packed from OWN registers (no exchange)
  {
    float q0[4], q1[4];
    float sq = 0.f, sk = 0.f;
#pragma unroll
    for (int r = 0; r < 4; ++r) {
      q0[r] = acc[0][r] + ((const float*)&qb0)[r];
      q1[r] = acc[1][r] + ((const float*)&qb1)[r];
      sq += q0[r] * q0[r] + q1[r] * q1[r];
      sk += acc[2][r] * acc[2][r] + acc[3][r] * acc[3][r];
    }
    sq += __shfl_xor(sq, 16); sq += __shfl_xor(sq, 32);
    sk += __shfl_xor(sk, 16); sk += __shfl_xor(sk, 32);
    const float rq = sl / fmaxf(sqrtf(sq), 1e-12f);
    const float rk = 1.f / fmaxf(sqrtf(sk), 1e-12f);
    u32x4 av;
    av[0] = cvtpk(q0[0] * rq, q0[1] * rq);
    av[1] = cvtpk(q0[2] * rq, q0[3] * rq);
    av[2] = cvtpk(q1[0] * rq, q1[1] * rq);
    av[3] = cvtpk(q1[2] * rq, q1[3] * rq);
    aq = __builtin_bit_cast(bf16x8, av);
    // k-hat -> LDS: the lane's 8 d-values ARE logical chunk lg -> one b128
    u16x8 kp;
#pragma unroll
    for (int r = 0; r < 4; ++r) {
      kp[r] = f2bfu(acc[2][r] * rk);
      kp[4 + r] = f2bfu(acc[3][r] * rk);
    }
    *(u16x8*)(lk + tok * 32 + (swc(tok, lg) << 3)) = kp;
  }
  // v -> LDS, token-permuted: token mm=tok&31 stored at within-chunk pos
  // q8*4 + (mm&3) of logical chunk (tok>>5)*4 + ((mm>>2)&3); q8 = mm>>4.
  {
    const int clog = ((tok >> 5) << 2) + ((l16 >> 2) & 3);
    const int wpos = ((tok >> 4) & 1) * 4 + (l16 & 3);
#pragma unroll
    for (int mf = 0; mf < 2; ++mf) {
      const float4 vb = *(const float4*)(v_bias + h * 32 + mf * 16 + lg * 4);
#pragma unroll
      for (int r = 0; r < 4; ++r) {
        const int dd = mf * 16 + lg * 4 + r;
        const float vv = acc[4 + mf][r] + ((const float*)&vb)[r];
        lv[dd * 256 + (((clog ^ dd) & 31) << 3) + wpos] = f2bfu(vv);
      }
    }
  }
  __syncthreads();

  // ---- phase B: swapped QK^T + online softmax + SWAPPED PV ----
  // s[.][r] = S[m = cc*32 (+16) + lg*4+r][q=l16]; stats per q=l16 (own).
  // PV: o = mfma(bv, pa) -> o[d = lg*4+r][q = l16]: rescale is lane-local.
  const int q = wid * 16 + l16;
  const unsigned short* rbp = rpbn + (h << 16) + (q << 8) + lg * 4;
  const float* mbp = mask + (w << 16) + (q << 8) + lg * 4;

  float mx = -3.0e38f, sm = 0.f;
  f32x4 o0 = (f32x4){0.f, 0.f, 0.f, 0.f}, o1 = (f32x4){0.f, 0.f, 0.f, 0.f};

#pragma unroll 2
  for (int cc = 0; cc < 8; ++cc) {
    const int m0 = cc * 32 + l16;
    const bf16x8 bk0 = lds8(lk + m0 * 32 + (swc(m0, lg) << 3));
    f32x4 s0 = mfma16(bk0, aq, (f32x4){0.f, 0.f, 0.f, 0.f});
    const int m1 = m0 + 16;
    const bf16x8 bk1 = lds8(lk + m1 * 32 + (swc(m1, lg) << 3));
    f32x4 s1 = mfma16(bk1, aq, (f32x4){0.f, 0.f, 0.f, 0.f});
    // bias (natural layout; m = cc*32 (+16) + lg*4 + r)
    {
      const u16x4 rv0 = *(const u16x4*)(rbp + cc * 32);
      const float4 mv0 = *(const float4*)(mbp + cc * 32);
      s0[0] = fmaf(mv0.x, LOG2EF, s0[0] + h2f(rv0[0]));
      s0[1] = fmaf(mv0.y, LOG2EF, s0[1] + h2f(rv0[1]));
      s0[2] = fmaf(mv0.z, LOG2EF, s0[2] + h2f(rv0[2]));
      s0[3] = fmaf(mv0.w, LOG2EF, s0[3] + h2f(rv0[3]));
      const u16x4 rv1 = *(const u16x4*)(rbp + cc * 32 + 16);
      const float4 mv1 = *(const float4*)(mbp + cc * 32 + 16);
      s1[0] = fmaf(mv1.x, LOG2EF, s1[0] + h2f(rv1[0]));
      s1[1] = fmaf(mv1.y, LOG2EF, s1[1] + h2f(rv1[1]));
      s1[2] = fmaf(mv1.z, LOG2EF, s1[2] + h2f(rv1[2]));
      s1[3] = fmaf(mv1.w, LOG2EF, s1[3] + h2f(rv1[3]));
    }
    // chunk max over 32 m (8 in-lane + lg reduce); uniform across lg
    float cmax = fmaxf(fmaxf(fmaxf(s0[0], s0[1]), fmaxf(s0[2], s0[3])),
                       fmaxf(fmaxf(s1[0], s1[1]), fmaxf(s1[2], s1[3])));
    cmax = fmaxf(cmax, __shfl_xor(cmax, 16));
    cmax = fmaxf(cmax, __shfl_xor(cmax, 32));
    // exact defer: rescale only when the running max actually grows;
    // o rows are this lane's own q -> NO broadcast needed
    if (!__all(cmax <= mx)) {
      const float mnew = fmaxf(mx, cmax);
      const float factor = fexp2(mx - mnew);
      sm *= factor;
      o0 *= factor;
      o1 *= factor;
      mx = mnew;
    }
    // p = exp2(s - mx); partial denominator; pack OWN values -> pa (B-frag)
    const float p00 = fexp2(s0[0] - mx), p01 = fexp2(s0[1] - mx);
    const float p02 = fexp2(s0[2] - mx), p03 = fexp2(s0[3] - mx);
    const float p10 = fexp2(s1[0] - mx), p11 = fexp2(s1[1] - mx);
    const float p12 = fexp2(s1[2] - mx), p13 = fexp2(s1[3] - mx);
    sm += ((p00 + p01) + (p02 + p03)) + ((p10 + p11) + (p12 + p13));
    u32x4 pw;
    pw[0] = cvtpk(p00, p01);
    pw[1] = cvtpk(p02, p03);
    pw[2] = cvtpk(p10, p11);
    pw[3] = cvtpk(p12, p13);
    const bf16x8 pa = __builtin_bit_cast(bf16x8, pw);
    // V-frags as A operand: rows d = l16 (+16), k-slot lg (token-permuted lv)
    const bf16x8 bv0 = lds8(lv + l16 * 256 + ((((cc * 4 + lg) ^ l16) & 31) << 3));
    const int d1 = 16 + l16;
    const bf16x8 bv1 = lds8(lv + d1 * 256 + ((((cc * 4 + lg) ^ d1) & 31) << 3));
    __builtin_amdgcn_s_setprio(1);
    o0 = mfma16(bv0, pa, o0);
    o1 = mfma16(bv1, pa, o1);
    __builtin_amdgcn_s_setprio(0);
  }
  // total denominator = sum of the 4 lg-group partials (factor history is
  // uniform across lg, so partials add linearly).
  sm += __shfl_xor(sm, 16);
  sm += __shfl_xor(sm, 32);
  const float inv = 1.f / sm;  // own q-row -> no broadcast
  // O write: lane (lg,l16) holds o[d = lg*4+r (+16)][q = tok]
  {
    const int row = (b * 256 + tok) << 8;
    u16x4 w0, w1;
#pragma unroll
    for (int r = 0; r < 4; ++r) {
      w0[r] = f2bfu(o0[r] * inv);
      w1[r] = f2bfu(o1[r] * inv);
    }
    *(u16x4*)(Obuf + row + h * 32 + lg * 4) = w0;
    *(u16x4*)(Obuf + row + h * 32 + 16 + lg * 4) = w1;
  }
}

// ---------------- out = O @ proj_w^T + proj_b (fp32) ----------------
__global__ __launch_bounds__(256, 2) void k_proj(
    const unsigned short* __restrict__ Obuf, const unsigned short* __restrict__ wproj,
    const float* __restrict__ proj_b, float* __restrict__ out) {
  __shared__ unsigned short la[128 * 32];
  __shared__ unsigned short lb[128 * 32];
  const int rb = blockIdx.x >> 1, cb = blockIdx.x & 1;
  const int tid = threadIdx.x, lane = tid & 63, wid = tid >> 6;
  const int wr = wid >> 1, wc = wid & 1;
  const int l16 = lane & 15, lg = lane >> 4;
  f32x4 acc[4][4];
#pragma unroll
  for (int i = 0; i < 4; ++i)
#pragma unroll
    for (int j = 0; j < 4; ++j) acc[i][j] = (f32x4){0.f, 0.f, 0.f, 0.f};
  for (int kt = 0; kt < 8; ++kt) {
    const int k0 = kt * 32;
#pragma unroll
    for (int it = 0; it < 2; ++it) {
      const int task = it * 256 + tid;
      const int row = task >> 2, c = task & 3;
      u16x8 va = *(const u16x8*)(Obuf + (rb * 128 + row) * 256 + k0 + c * 8);
      *(u16x8*)(la + row * 32 + ((c ^ (row & 3)) << 3)) = va;
      u16x8 vb = *(const u16x8*)(wproj + (cb * 128 + row) * 256 + k0 + c * 8);
      *(u16x8*)(lb + row * 32 + ((c ^ (row & 3)) << 3)) = vb;
    }
    __syncthreads();
    bf16x8 a[4];
#pragma unroll
    for (int af = 0; af < 4; ++af) {
      const int rr = wr * 64 + af * 16 + l16;
      a[af] = lds8(la + rr * 32 + ((lg ^ (rr & 3)) << 3));
    }
#pragma unroll
    for (int cf = 0; cf < 4; ++cf) {
      const int ccc = wc * 64 + cf * 16 + l16;
      bf16x8 bfr = lds8(lb + ccc * 32 + ((lg ^ (ccc & 3)) << 3));
#pragma unroll
      for (int af = 0; af < 4; ++af) acc[af][cf] = mfma16(a[af], bfr, acc[af][cf]);
    }
    __syncthreads();
  }
#pragma unroll
  for (int cf = 0; cf < 4; ++cf) {
    const int col = cb * 128 + wc * 64 + cf * 16 + l16;
    const float pb = proj_b[col];
#pragma unroll
    for (int af = 0; af < 4; ++af)
#pragma unroll
      for (int r = 0; r < 4; ++r) {
        const int row = rb * 128 + wr * 64 + af * 16 + lg * 4 + r;
        out[row * 256 + col] = acc[af][cf][r] + pb;
      }
  }
}

extern "C" void kernel_launch(void* const* d_in, const int* in_sizes, int n_in,
                              void* d_out, int out_size, void* d_ws, size_t ws_size,
                              hipStream_t stream) {
  (void)in_sizes; (void)n_in; (void)out_size; (void)ws_size;
  const float* x = (const float*)d_in[0];
  const float* mask = (const float*)d_in[1];
  const float* qkv_w = (const float*)d_in[2];
  const float* q_bias = (const float*)d_in[3];
  const float* v_bias = (const float*)d_in[4];
  const float* logit_scale = (const float*)d_in[5];
  const float* cpb_w1 = (const float*)d_in[6];
  const float* cpb_b1 = (const float*)d_in[7];
  const float* cpb_w2 = (const float*)d_in[8];
  const float* proj_w = (const float*)d_in[9];
  const float* proj_b = (const float*)d_in[10];
  float* out = (float*)d_out;
  char* ws = (char*)d_ws;

  // workspace layout (~102.3 MB)
  unsigned short* xbb = (unsigned short*)(ws + 0);            // 33,554,432 (half batch)
  unsigned short* Obuf = (unsigned short*)(ws + 33554432);    // 67,108,864
  unsigned short* rpbn = (unsigned short*)(ws + 100663296);   // 1,048,576
  float* bt = (float*)(ws + 101711872);                       // 30,752
  unsigned short* wqkv = (unsigned short*)(ws + 101742624);   // 393,216
  unsigned short* wproj = (unsigned short*)(ws + 102135840);  // 131,072

  k_cvt_w<<<dim3(1024), dim3(256), 0, stream>>>(qkv_w, proj_w, wqkv, wproj);
  k_cpb<<<dim3(961), dim3(64), 0, stream>>>(cpb_w1, cpb_b1, cpb_w2, bt);
  k_rpb<<<dim3(2048), dim3(256), 0, stream>>>(bt, rpbn);

  k_cvt_x<<<dim3(8192), dim3(256), 0, stream>>>(x, xbb);
  k_attn<<<dim3(2048), dim3(1024), 0, stream>>>(xbb, q_bias, v_bias, logit_scale,
                                                wqkv, rpbn, mask, Obuf, 0);
  k_cvt_x<<<dim3(8192), dim3(256), 0, stream>>>(x + 16777216, xbb);
  k_attn<<<dim3(2048), dim3(1024), 0, stream>>>(xbb, q_bias, v_bias, logit_scale,
                                                wqkv, rpbn, mask, Obuf, 256);

  k_proj<<<dim3(2048), dim3(256), 0, stream>>>(Obuf, wproj, proj_b, out);
}

// Round 10
// 415.681 us; speedup vs baseline: 1.0114x; 1.0114x over previous
//
#include <hip/hip_runtime.h>
#include <hip/hip_bf16.h>
#include <hip/hip_fp16.h>

// SwinV2 window attention, MI355X/gfx950.
// Pipeline: cvt_w, cpb, rpb (1MB natural-layout bias, log2e-folded),
//           2x [cvt_x(half) -> attn(half)], proj.
// attn: 1024 thr / 16 waves, 2 blocks/CU (LDS 77824, VGPR<=64).
// R10: de-convoy (per-wave chunk start offset wid&7 — online softmax is
// order-independent), full-unroll phase B with bias loads software-pipelined
// one chunk ahead (chunk 0 issued before the phase-A->B barrier), cvtpk
// packing for lk/lv/O (1 instr per 2 values), setprio removed (m190).

#define LOG100F 4.605170185988091f
#define LOG2EF 1.4426950408889634f

typedef __attribute__((ext_vector_type(8))) __bf16 bf16x8;
typedef __attribute__((ext_vector_type(4))) float f32x4;
typedef __attribute__((ext_vector_type(8))) unsigned short u16x8;
typedef __attribute__((ext_vector_type(4))) unsigned short u16x4;
typedef __attribute__((ext_vector_type(4))) unsigned int u32x4;
typedef __attribute__((ext_vector_type(2))) unsigned int u32x2;

__device__ __forceinline__ unsigned short f2bfu(float f) {
  __hip_bfloat16 b = __float2bfloat16(f);
  return __builtin_bit_cast(unsigned short, b);
}
__device__ __forceinline__ unsigned short f2h(float f) {
  __half hv = __float2half(f);
  return __builtin_bit_cast(unsigned short, hv);
}
__device__ __forceinline__ float h2f(unsigned short b) {
  return __half2float(__builtin_bit_cast(__half, b));
}
__device__ __forceinline__ bf16x8 lds8(const unsigned short* p) {
  u16x8 v = *(const u16x8*)p;
  return __builtin_bit_cast(bf16x8, v);
}
__device__ __forceinline__ f32x4 mfma16(bf16x8 a, bf16x8 b, f32x4 c) {
  return __builtin_amdgcn_mfma_f32_16x16x32_bf16(a, b, c, 0, 0, 0);
}
__device__ __forceinline__ float fexp2(float x) {
#if __has_builtin(__builtin_amdgcn_exp2f)
  return __builtin_amdgcn_exp2f(x);
#else
  return exp2f(x);
#endif
}
// pack two f32 -> one u32 of 2 bf16 (lo = a, hi = b), RNE
__device__ __forceinline__ unsigned int cvtpk(float a, float b) {
  unsigned int r;
  asm("v_cvt_pk_bf16_f32 %0, %1, %2" : "=v"(r) : "v"(a), "v"(b));
  return r;
}
// 16B-chunk XOR swizzle for [R][32]-u16 tiles: <=2-way on ds_read_b128
__device__ __forceinline__ int swc(int row, int kchunk) {
  return (kchunk ^ (row & 3) ^ ((row >> 2) & 3)) & 3;
}
__device__ __forceinline__ void gload_lds16(const void* g, void* l) {
  __builtin_amdgcn_global_load_lds(
      (const __attribute__((address_space(1))) void*)g,
      (__attribute__((address_space(3))) void*)l, 16, 0, 0);
}

// ---------------- weights -> bf16 ----------------
__global__ void k_cvt_w(const float* __restrict__ qkv_w, const float* __restrict__ proj_w,
                        unsigned short* __restrict__ wqkv, unsigned short* __restrict__ wproj) {
  const int t = blockIdx.x * 256 + threadIdx.x;
  if (t < 768 * 256) {
    wqkv[t] = f2bfu(qkv_w[t]);
  } else {
    const int t2 = t - 768 * 256;
    wproj[t2] = f2bfu(proj_w[t2]);
  }
}

// ---------------- x -> bf16 (half batch per call) ----------------
__global__ void k_cvt_x(const float* __restrict__ x, unsigned short* __restrict__ xb) {
  const int t = blockIdx.x * 256 + threadIdx.x;
  const float4 a = *(const float4*)(x + (size_t)t * 8);
  const float4 c = *(const float4*)(x + (size_t)t * 8 + 4);
  u32x4 ov;
  ov[0] = cvtpk(a.x, a.y);
  ov[1] = cvtpk(a.z, a.w);
  ov[2] = cvtpk(c.x, c.y);
  ov[3] = cvtpk(c.z, c.w);
  *(u32x4*)(xb + (size_t)t * 8) = ov;
}

// ---------------- CPB MLP -> bias_table[961][8] ----------------
__global__ void k_cpb(const float* __restrict__ w1, const float* __restrict__ b1,
                      const float* __restrict__ w2, float* __restrict__ bt) {
  const int row = blockIdx.x;
  const int lane = threadIdx.x;
  const int i = row / 31, j = row % 31;
  float x0 = (i - 15) * (1.0f / 15.0f);
  float x1 = (j - 15) * (1.0f / 15.0f);
  float v0 = log2f(fmaf(8.0f, fabsf(x0), 1.0f)) * (1.0f / 3.0f); v0 = x0 < 0.0f ? -v0 : v0;
  float v1 = log2f(fmaf(8.0f, fabsf(x1), 1.0f)) * (1.0f / 3.0f); v1 = x1 < 0.0f ? -v1 : v1;
  float a[8] = {0.f, 0.f, 0.f, 0.f, 0.f, 0.f, 0.f, 0.f};
  for (int jj = lane; jj < 512; jj += 64) {
    float hv = fmaf(w1[2 * jj], v0, fmaf(w1[2 * jj + 1], v1, b1[jj]));
    hv = fmaxf(hv, 0.0f);
#pragma unroll
    for (int hh = 0; hh < 8; ++hh) a[hh] = fmaf(hv, w2[hh * 512 + jj], a[hh]);
  }
#pragma unroll
  for (int hh = 0; hh < 8; ++hh) {
#pragma unroll
    for (int mm = 1; mm < 64; mm <<= 1) a[hh] += __shfl_xor(a[hh], mm);
  }
  float outv = a[0];
#pragma unroll
  for (int hh = 1; hh < 8; ++hh)
    if (lane == hh) outv = a[hh];
  if (lane < 8) bt[row * 8 + lane] = outv;
}

// ------- rpbn[h][n][m] = fp16(log2e * 16*sigmoid(bt[idx(n,m)][h])) -------
__global__ void k_rpb(const float* __restrict__ bt, unsigned short* __restrict__ rpbn) {
  const int t = blockIdx.x * 256 + threadIdx.x;  // 2048 blocks -> 524288
  const int m = t & 255, n = (t >> 8) & 255, h = t >> 16;
  const int ih = n >> 4, iw = n & 15, jh = m >> 4, jw = m & 15;
  const int idx = (ih - jh + 15) * 31 + (iw - jw + 15);
  const float bv = bt[idx * 8 + h];
  rpbn[t] = f2h(LOG2EF * 16.0f / (1.0f + __expf(-bv)));
}

// ---------------- fused qkv + cosine attention, per (b,h) ----------------
__global__ __launch_bounds__(1024, 8) void k_attn(
    const unsigned short* __restrict__ xb, const float* __restrict__ q_bias,
    const float* __restrict__ v_bias, const float* __restrict__ logit_scale,
    const unsigned short* __restrict__ wqkv, const unsigned short* __restrict__ rpbn,
    const float* __restrict__ mask, unsigned short* __restrict__ Obuf, int b0) {
  // 77,824 B total -> 2 blocks/CU.
  __shared__ unsigned short lx[2][8192];  // x slice [256 tok][32 k], dbuf (phase A only)
  __shared__ unsigned short lw[2][3072];  // W_h slice [96][32], dbuf
  __shared__ unsigned short lk[8192];     // k-hat [256 tok][32 d], d-permuted chunks
  __shared__ unsigned short lv[8192];     // v^T  [32 d][256 tok], token-permuted chunks

  // XCD-aware map: bid = g*64 + h*8 + x (x = XCD = bid%8); bl = g*8 + x.
  const int bid = blockIdx.x;
  const int xcd = bid & 7, h = (bid >> 3) & 7, g = bid >> 6;
  const int bl = g * 8 + xcd;
  const int b = b0 + bl;
  const int w = b & 63;
  const int tid = threadIdx.x;
  const int lane = tid & 63, wid = tid >> 6;
  const int l16 = lane & 15, lg = lane >> 4;

  // ---- phase A: [96 wcols x 256 tok] = W_h . x^T, K=256 in 8 slices ----
  const int srow = wid * 16 + (lane >> 2);
  const int pc = lane & 3;
  const int xlc = (pc ^ (srow & 3) ^ ((srow >> 2) & 3)) & 3;
  const unsigned short* xsrc0 = xb + (((bl << 8) + srow) << 8) + (xlc << 3);
  const unsigned short* wsrc0 =
      wqkv + ((((srow >> 5) << 8) + h * 32 + (srow & 31)) << 8) + (xlc << 3);

  f32x4 acc[6];
#pragma unroll
  for (int i = 0; i < 6; ++i) acc[i] = (f32x4){0.f, 0.f, 0.f, 0.f};

  gload_lds16(xsrc0, &lx[0][wid * 512]);
  if (wid < 6) gload_lds16(wsrc0, &lw[0][wid * 512]);
  __syncthreads();

  for (int kt = 0; kt < 8; ++kt) {
    const int cur = kt & 1;
    if (kt < 7) {
      const int k0 = (kt + 1) << 5;
      gload_lds16(xsrc0 + k0, &lx[cur ^ 1][wid * 512]);
      if (wid < 6) gload_lds16(wsrc0 + k0, &lw[cur ^ 1][wid * 512]);
    }
    const unsigned short* lxb = lx[cur];
    const unsigned short* lwb = lw[cur];
    const int n = wid * 16 + l16;
    const bf16x8 ax = lds8(lxb + n * 32 + (swc(n, lg) << 3));
#pragma unroll
    for (int mf = 0; mf < 6; ++mf) {
      const int m = mf * 16 + l16;
      const bf16x8 aw = lds8(lwb + m * 32 + (swc(m, lg) << 3));
      acc[mf] = mfma16(aw, ax, acc[mf]);
    }
    __syncthreads();
  }

  // ---- epilogue: lane owns token tok = wid*16+l16; d = mf*16+lg*4+r ----
  // k-slot mapping (QK): slot lg, j<4 <-> d = lg*4+j ; j>=4 <-> d = 16+lg*4+(j-4).
  const float sl = __expf(fminf(logit_scale[h], LOG100F)) * LOG2EF;
  const int tok = wid * 16 + l16;
  const float4 qb0 = *(const float4*)(q_bias + h * 32 + lg * 4);
  const float4 qb1 = *(const float4*)(q_bias + h * 32 + 16 + lg * 4);

  bf16x8 aq;  // B-frag for QK, packed from OWN registers (no exchange)
  {
    float q0[4], q1[4];
    float sq = 0.f, sk = 0.f;
#pragma unroll
    for (int r = 0; r < 4; ++r) {
      q0[r] = acc[0][r] + ((const float*)&qb0)[r];
      q1[r] = acc[1][r] + ((const float*)&qb1)[r];
      sq += q0[r] * q0[r] + q1[r] * q1[r];
      sk += acc[2][r] * acc[2][r] + acc[3][r] * acc[3][r];
    }
    sq += __shfl_xor(sq, 16); sq += __shfl_xor(sq, 32);
    sk += __shfl_xor(sk, 16); sk += __shfl_xor(sk, 32);
    const float rq = sl / fmaxf(sqrtf(sq), 1e-12f);
    const float rk = 1.f / fmaxf(sqrtf(sk), 1e-12f);
    u32x4 av;
    av[0] = cvtpk(q0[0] * rq, q0[1] * rq);
    av[1] = cvtpk(q0[2] * rq, q0[3] * rq);
    av[2] = cvtpk(q1[0] * rq, q1[1] * rq);
    av[3] = cvtpk(q1[2] * rq, q1[3] * rq);
    aq = __builtin_bit_cast(bf16x8, av);
    // k-hat -> LDS: the lane's 8 d-values ARE logical chunk lg -> one b128
    u32x4 kp;
    kp[0] = cvtpk(acc[2][0] * rk, acc[2][1] * rk);
    kp[1] = cvtpk(acc[2][2] * rk, acc[2][3] * rk);
    kp[2] = cvtpk(acc[3][0] * rk, acc[3][1] * rk);
    kp[3] = cvtpk(acc[3][2] * rk, acc[3][3] * rk);
    *(u32x4*)(lk + tok * 32 + (swc(tok, lg) << 3)) = kp;
  }
  // v -> LDS, token-permuted: token mm=tok&31 stored at within-chunk pos
  // q8*4 + (mm&3) of logical chunk (tok>>5)*4 + ((mm>>2)&3); q8 = mm>>4.
  {
    const int clog = ((tok >> 5) << 2) + ((l16 >> 2) & 3);
    const int wpos = ((tok >> 4) & 1) * 4 + (l16 & 3);
#pragma unroll
    for (int mf = 0; mf < 2; ++mf) {
      const float4 vb = *(const float4*)(v_bias + h * 32 + mf * 16 + lg * 4);
      const unsigned int pa01 = cvtpk(acc[4 + mf][0] + vb.x, acc[4 + mf][1] + vb.y);
      const unsigned int pa23 = cvtpk(acc[4 + mf][2] + vb.z, acc[4 + mf][3] + vb.w);
      const int d0 = mf * 16 + lg * 4;
      lv[(d0 + 0) * 256 + ((((clog ^ (d0 + 0)) & 31)) << 3) + wpos] = (unsigned short)pa01;
      lv[(d0 + 1) * 256 + ((((clog ^ (d0 + 1)) & 31)) << 3) + wpos] = (unsigned short)(pa01 >> 16);
      lv[(d0 + 2) * 256 + ((((clog ^ (d0 + 2)) & 31)) << 3) + wpos] = (unsigned short)pa23;
      lv[(d0 + 3) * 256 + ((((clog ^ (d0 + 3)) & 31)) << 3) + wpos] = (unsigned short)(pa23 >> 16);
    }
  }

  // ---- phase B setup: bias prefetch for this wave's FIRST chunk issues
  // BEFORE the barrier (global loads, independent of LDS) ----
  const int q = wid * 16 + l16;
  const unsigned short* rbp = rpbn + (h << 16) + (q << 8) + lg * 4;
  const float* mbp = mask + (w << 16) + (q << 8) + lg * 4;
  const int st = wid & 7;  // de-convoy: per-wave chunk start offset

  u16x4 rvA = *(const u16x4*)(rbp + st * 32);
  u16x4 rvB = *(const u16x4*)(rbp + st * 32 + 16);
  float4 mvA = *(const float4*)(mbp + st * 32);
  float4 mvB = *(const float4*)(mbp + st * 32 + 16);

  __syncthreads();

  // ---- phase B: swapped QK^T + online softmax + SWAPPED PV ----
  // s[.][r] = S[m = cc*32 (+16) + lg*4+r][q=l16]; stats per q=l16 (own).
  // PV: o = mfma(bv, pa) -> o[d = lg*4+r][q = l16]: rescale is lane-local.
  float mx = -3.0e38f, sm = 0.f;
  f32x4 o0 = (f32x4){0.f, 0.f, 0.f, 0.f}, o1 = (f32x4){0.f, 0.f, 0.f, 0.f};

#pragma unroll
  for (int ci = 0; ci < 8; ++ci) {
    const int cc = (st + ci) & 7;
    const int m0 = cc * 32 + l16;
    const bf16x8 bk0 = lds8(lk + m0 * 32 + (swc(m0, lg) << 3));
    f32x4 s0 = mfma16(bk0, aq, (f32x4){0.f, 0.f, 0.f, 0.f});
    const int m1 = m0 + 16;
    const bf16x8 bk1 = lds8(lk + m1 * 32 + (swc(m1, lg) << 3));
    f32x4 s1 = mfma16(bk1, aq, (f32x4){0.f, 0.f, 0.f, 0.f});
    // rotate bias regs; issue NEXT chunk's loads now (latency hides under
    // the softmax work below)
    const u16x4 crA = rvA, crB = rvB;
    const float4 cmA = mvA, cmB = mvB;
    if (ci < 7) {
      const int nc = (st + ci + 1) & 7;
      rvA = *(const u16x4*)(rbp + nc * 32);
      rvB = *(const u16x4*)(rbp + nc * 32 + 16);
      mvA = *(const float4*)(mbp + nc * 32);
      mvB = *(const float4*)(mbp + nc * 32 + 16);
    }
    // bias add (natural layout; m = cc*32 (+16) + lg*4 + r)
    s0[0] = fmaf(cmA.x, LOG2EF, s0[0] + h2f(crA[0]));
    s0[1] = fmaf(cmA.y, LOG2EF, s0[1] + h2f(crA[1]));
    s0[2] = fmaf(cmA.z, LOG2EF, s0[2] + h2f(crA[2]));
    s0[3] = fmaf(cmA.w, LOG2EF, s0[3] + h2f(crA[3]));
    s1[0] = fmaf(cmB.x, LOG2EF, s1[0] + h2f(crB[0]));
    s1[1] = fmaf(cmB.y, LOG2EF, s1[1] + h2f(crB[1]));
    s1[2] = fmaf(cmB.z, LOG2EF, s1[2] + h2f(crB[2]));
    s1[3] = fmaf(cmB.w, LOG2EF, s1[3] + h2f(crB[3]));
    // chunk max over 32 m (8 in-lane + lg reduce); uniform across lg
    float cmax = fmaxf(fmaxf(fmaxf(s0[0], s0[1]), fmaxf(s0[2], s0[3])),
                       fmaxf(fmaxf(s1[0], s1[1]), fmaxf(s1[2], s1[3])));
    cmax = fmaxf(cmax, __shfl_xor(cmax, 16));
    cmax = fmaxf(cmax, __shfl_xor(cmax, 32));
    // exact defer: rescale only when the running max actually grows;
    // o rows are this lane's own q -> lane-local rescale
    if (!__all(cmax <= mx)) {
      const float mnew = fmaxf(mx, cmax);
      const float factor = fexp2(mx - mnew);
      sm *= factor;
      o0 *= factor;
      o1 *= factor;
      mx = mnew;
    }
    // p = exp2(s - mx); partial denominator; pack OWN values -> pa (B-frag)
    const float p00 = fexp2(s0[0] - mx), p01 = fexp2(s0[1] - mx);
    const float p02 = fexp2(s0[2] - mx), p03 = fexp2(s0[3] - mx);
    const float p10 = fexp2(s1[0] - mx), p11 = fexp2(s1[1] - mx);
    const float p12 = fexp2(s1[2] - mx), p13 = fexp2(s1[3] - mx);
    sm += ((p00 + p01) + (p02 + p03)) + ((p10 + p11) + (p12 + p13));
    u32x4 pw;
    pw[0] = cvtpk(p00, p01);
    pw[1] = cvtpk(p02, p03);
    pw[2] = cvtpk(p10, p11);
    pw[3] = cvtpk(p12, p13);
    const bf16x8 pa = __builtin_bit_cast(bf16x8, pw);
    // V-frags as A operand: rows d = l16 (+16), k-slot lg (token-permuted lv)
    const bf16x8 bv0 = lds8(lv + l16 * 256 + ((((cc * 4 + lg) ^ l16) & 31) << 3));
    const int d1 = 16 + l16;
    const bf16x8 bv1 = lds8(lv + d1 * 256 + ((((cc * 4 + lg) ^ d1) & 31) << 3));
    o0 = mfma16(bv0, pa, o0);
    o1 = mfma16(bv1, pa, o1);
  }
  // total denominator = sum of the 4 lg-group partials (factor history is
  // uniform across lg, so partials add linearly).
  sm += __shfl_xor(sm, 16);
  sm += __shfl_xor(sm, 32);
  const float inv = 1.f / sm;  // own q-row -> no broadcast
  // O write: lane (lg,l16) holds o[d = lg*4+r (+16)][q = tok]
  {
    const int row = (b * 256 + tok) << 8;
    u32x2 wa, wb;
    wa[0] = cvtpk(o0[0] * inv, o0[1] * inv);
    wa[1] = cvtpk(o0[2] * inv, o0[3] * inv);
    wb[0] = cvtpk(o1[0] * inv, o1[1] * inv);
    wb[1] = cvtpk(o1[2] * inv, o1[3] * inv);
    *(u32x2*)(Obuf + row + h * 32 + lg * 4) = wa;
    *(u32x2*)(Obuf + row + h * 32 + 16 + lg * 4) = wb;
  }
}

// ---------------- out = O @ proj_w^T + proj_b (fp32) ----------------
__global__ __launch_bounds__(256, 2) void k_proj(
    const unsigned short* __restrict__ Obuf, const unsigned short* __restrict__ wproj,
    const float* __restrict__ proj_b, float* __restrict__ out) {
  __shared__ unsigned short la[128 * 32];
  __shared__ unsigned short lb[128 * 32];
  const int rb = blockIdx.x >> 1, cb = blockIdx.x & 1;
  const int tid = threadIdx.x, lane = tid & 63, wid = tid >> 6;
  const int wr = wid >> 1, wc = wid & 1;
  const int l16 = lane & 15, lg = lane >> 4;
  f32x4 acc[4][4];
#pragma unroll
  for (int i = 0; i < 4; ++i)
#pragma unroll
    for (int j = 0; j < 4; ++j) acc[i][j] = (f32x4){0.f, 0.f, 0.f, 0.f};
  for (int kt = 0; kt < 8; ++kt) {
    const int k0 = kt * 32;
#pragma unroll
    for (int it = 0; it < 2; ++it) {
      const int task = it * 256 + tid;
      const int row = task >> 2, c = task & 3;
      u16x8 va = *(const u16x8*)(Obuf + (rb * 128 + row) * 256 + k0 + c * 8);
      *(u16x8*)(la + row * 32 + ((c ^ (row & 3)) << 3)) = va;
      u16x8 vb = *(const u16x8*)(wproj + (cb * 128 + row) * 256 + k0 + c * 8);
      *(u16x8*)(lb + row * 32 + ((c ^ (row & 3)) << 3)) = vb;
    }
    __syncthreads();
    bf16x8 a[4];
#pragma unroll
    for (int af = 0; af < 4; ++af) {
      const int rr = wr * 64 + af * 16 + l16;
      a[af] = lds8(la + rr * 32 + ((lg ^ (rr & 3)) << 3));
    }
#pragma unroll
    for (int cf = 0; cf < 4; ++cf) {
      const int ccc = wc * 64 + cf * 16 + l16;
      bf16x8 bfr = lds8(lb + ccc * 32 + ((lg ^ (ccc & 3)) << 3));
#pragma unroll
      for (int af = 0; af < 4; ++af) acc[af][cf] = mfma16(a[af], bfr, acc[af][cf]);
    }
    __syncthreads();
  }
#pragma unroll
  for (int cf = 0; cf < 4; ++cf) {
    const int col = cb * 128 + wc * 64 + cf * 16 + l16;
    const float pb = proj_b[col];
#pragma unroll
    for (int af = 0; af < 4; ++af)
#pragma unroll
      for (int r = 0; r < 4; ++r) {
        const int row = rb * 128 + wr * 64 + af * 16 + lg * 4 + r;
        out[row * 256 + col] = acc[af][cf][r] + pb;
      }
  }
}

extern "C" void kernel_launch(void* const* d_in, const int* in_sizes, int n_in,
                              void* d_out, int out_size, void* d_ws, size_t ws_size,
                              hipStream_t stream) {
  (void)in_sizes; (void)n_in; (void)out_size; (void)ws_size;
  const float* x = (const float*)d_in[0];
  const float* mask = (const float*)d_in[1];
  const float* qkv_w = (const float*)d_in[2];
  const float* q_bias = (const float*)d_in[3];
  const float* v_bias = (const float*)d_in[4];
  const float* logit_scale = (const float*)d_in[5];
  const float* cpb_w1 = (const float*)d_in[6];
  const float* cpb_b1 = (const float*)d_in[7];
  const float* cpb_w2 = (const float*)d_in[8];
  const float* proj_w = (const float*)d_in[9];
  const float* proj_b = (const float*)d_in[10];
  float* out = (float*)d_out;
  char* ws = (char*)d_ws;

  // workspace layout (~102.3 MB)
  unsigned short* xbb = (unsigned short*)(ws + 0);            // 33,554,432 (half batch)
  unsigned short* Obuf = (unsigned short*)(ws + 33554432);    // 67,108,864
  unsigned short* rpbn = (unsigned short*)(ws + 100663296);   // 1,048,576
  float* bt = (float*)(ws + 101711872);                       // 30,752
  unsigned short* wqkv = (unsigned short*)(ws + 101742624);   // 393,216
  unsigned short* wproj = (unsigned short*)(ws + 102135840);  // 131,072

  k_cvt_w<<<dim3(1024), dim3(256), 0, stream>>>(qkv_w, proj_w, wqkv, wproj);
  k_cpb<<<dim3(961), dim3(64), 0, stream>>>(cpb_w1, cpb_b1, cpb_w2, bt);
  k_rpb<<<dim3(2048), dim3(256), 0, stream>>>(bt, rpbn);

  k_cvt_x<<<dim3(8192), dim3(256), 0, stream>>>(x, xbb);
  k_attn<<<dim3(2048), dim3(1024), 0, stream>>>(xbb, q_bias, v_bias, logit_scale,
                                                wqkv, rpbn, mask, Obuf, 0);
  k_cvt_x<<<dim3(8192), dim3(256), 0, stream>>>(x + 16777216, xbb);
  k_attn<<<dim3(2048), dim3(1024), 0, stream>>>(xbb, q_bias, v_bias, logit_scale,
                                                wqkv, rpbn, mask, Obuf, 256);

  k_proj<<<dim3(2048), dim3(256), 0, stream>>>(Obuf, wproj, proj_b, out);
}